// Round 2
// baseline (40013.290 us; speedup 1.0000x reference)
//
#include <hip/hip_runtime.h>
#include <cstdint>
#include <cmath>

// ---------------- constants ----------------
#define BB 32
#define TT 512
#define EE 768
#define HH 3132
#define HP 3136   // H padded to mult of 64 (MFMA tiles)
#define OO 19

typedef __attribute__((ext_vector_type(8))) short s8v;
typedef __attribute__((ext_vector_type(4))) float f4v;

__device__ __forceinline__ unsigned short f2bf(float f) {
    uint32_t u = __float_as_uint(f);
    uint32_t r = u + 0x7FFFu + ((u >> 16) & 1u);
    return (unsigned short)(r >> 16);
}
__device__ __forceinline__ float bf2f(unsigned short h) {
    return __uint_as_float(((uint32_t)h) << 16);
}

// ---------------- LN over input x, write transposed hi/lo bf16 [T][B][E] ----------------
__global__ void ln_x_k(const float* __restrict__ x, const float* __restrict__ g,
                       const float* __restrict__ be, unsigned short* __restrict__ xnhi,
                       unsigned short* __restrict__ xnlo) {
    int bt = blockIdx.x;            // b*512 + t
    int b = bt >> 9, t = bt & 511;
    const float* row = x + ((size_t)b * TT + t) * EE;
    int tid = threadIdx.x;
    float v0 = row[tid], v1 = row[tid + 256], v2 = row[tid + 512];
    float s = v0 + v1 + v2, s2 = v0 * v0 + v1 * v1 + v2 * v2;
    for (int o = 32; o; o >>= 1) { s += __shfl_xor(s, o); s2 += __shfl_xor(s2, o); }
    __shared__ float r1[4], r2[4];
    int wid = tid >> 6, lane = tid & 63;
    if (lane == 0) { r1[wid] = s; r2[wid] = s2; }
    __syncthreads();
    s = r1[0] + r1[1] + r1[2] + r1[3];
    s2 = r2[0] + r2[1] + r2[2] + r2[3];
    float m = s / (float)EE, var = s2 / (float)EE - m * m;
    float inv = rsqrtf(var + 1e-5f);
    size_t ro = ((size_t)t * BB + b) * EE;
    float vals[3] = {v0, v1, v2};
#pragma unroll
    for (int i = 0; i < 3; i++) {
        int e = tid + i * 256;
        float o = (vals[i] - m) * inv * g[e] + be[e];
        unsigned short hb = f2bf(o);
        xnhi[ro + e] = hb;
        xnlo[ro + e] = f2bf(o - bf2f(hb));
    }
}

// ---------------- cast f32 [N][K] -> bf16 [Np][Kp], zero pads ----------------
__global__ void castpad_k(const float* __restrict__ in, int N, int K,
                          unsigned short* __restrict__ out, int Np, int Kp) {
    size_t gid = (size_t)blockIdx.x * 256 + threadIdx.x;
    if (gid >= (size_t)Np * Kp) return;
    int n = (int)(gid / Kp), k = (int)(gid % Kp);
    out[gid] = (n < N && k < K) ? f2bf(in[(size_t)n * K + k]) : (unsigned short)0;
}

// ---------------- split cast f32 [N][K] -> hi/lo bf16 [Np][Kp] ----------------
__global__ void castsplit_k(const float* __restrict__ in, int N, int K,
                            unsigned short* __restrict__ hi, unsigned short* __restrict__ lo,
                            int Np, int Kp) {
    size_t gid = (size_t)blockIdx.x * 256 + threadIdx.x;
    if (gid >= (size_t)Np * Kp) return;
    int n = (int)(gid / Kp), k = (int)(gid % Kp);
    float v = (n < N && k < K) ? in[(size_t)n * K + k] : 0.0f;
    unsigned short hb = f2bf(v);
    hi[gid] = hb;
    lo[gid] = f2bf(v - bf2f(hb));
}

// ---------------- transpose cast: out[c][r] = in[r][c], f32->bf16 ----------------
__global__ void transcast_k(const float* __restrict__ in, int R, int C,
                            unsigned short* __restrict__ out, int Rp, int Cp) {
    __shared__ float tile[32][33];
    int c0 = blockIdx.x * 32, r0 = blockIdx.y * 32;
    int tx = threadIdx.x & 31, ty = threadIdx.x >> 5;
    for (int i = 0; i < 4; i++) {
        int r = r0 + ty + i * 8, c = c0 + tx;
        tile[ty + i * 8][tx] = (r < R && c < C) ? in[(size_t)r * C + c] : 0.0f;
    }
    __syncthreads();
    for (int i = 0; i < 4; i++) {
        int c = c0 + ty + i * 8, r = r0 + tx;
        if (c < Cp && r < Rp) out[(size_t)c * Rp + r] = f2bf(tile[tx][ty + i * 8]);
    }
}

__global__ void biascomb_k(const float* a, const float* b, float* o, int realN, int Np) {
    int gid = blockIdx.x * 256 + threadIdx.x;
    if (gid >= Np) return;
    o[gid] = (gid < realN) ? a[gid] + b[gid] : 0.0f;
}

// ---------------- big GEMM (split precision): out_f32[m][n] = sum_k A[m][k]*W[n][k], M=8192 ----------------
__global__ __launch_bounds__(256) void gemmbig_k(const unsigned short* __restrict__ Ahi,
                                                 const unsigned short* __restrict__ Alo,
                                                 const unsigned short* __restrict__ Whi,
                                                 const unsigned short* __restrict__ Wlo,
                                                 float* __restrict__ out,
                                                 int Kld, int Np, int ksteps) {
    int m0 = blockIdx.x * 32;
    int n0 = blockIdx.y * 64;
    int wid = threadIdx.x >> 6, lane = threadIdx.x & 63;
    int r = lane & 15, kg = lane >> 4;
    size_t woff = (size_t)(n0 + wid * 16 + r) * Kld + kg * 8;
    const unsigned short* Whr = Whi + woff;
    const unsigned short* Wlr = Wlo + woff;
    size_t aoff = (size_t)(m0 + r) * Kld + kg * 8;
    const unsigned short* Ah0 = Ahi + aoff;
    const unsigned short* Ah1 = Ah0 + (size_t)16 * Kld;
    const unsigned short* Al0 = Alo + aoff;
    const unsigned short* Al1 = Al0 + (size_t)16 * Kld;
    f4v acc0 = {0.f, 0.f, 0.f, 0.f}, acc1 = {0.f, 0.f, 0.f, 0.f};
#pragma unroll 4
    for (int s = 0; s < ksteps; s++) {
        s8v bh = *(const s8v*)(Whr + s * 32);
        s8v bl = *(const s8v*)(Wlr + s * 32);
        s8v a0h = *(const s8v*)(Ah0 + s * 32);
        s8v a1h = *(const s8v*)(Ah1 + s * 32);
        s8v a0l = *(const s8v*)(Al0 + s * 32);
        s8v a1l = *(const s8v*)(Al1 + s * 32);
        acc0 = __builtin_amdgcn_mfma_f32_16x16x32_bf16(a0h, bh, acc0, 0, 0, 0);
        acc1 = __builtin_amdgcn_mfma_f32_16x16x32_bf16(a1h, bh, acc1, 0, 0, 0);
        acc0 = __builtin_amdgcn_mfma_f32_16x16x32_bf16(a0l, bh, acc0, 0, 0, 0);
        acc1 = __builtin_amdgcn_mfma_f32_16x16x32_bf16(a1l, bh, acc1, 0, 0, 0);
        acc0 = __builtin_amdgcn_mfma_f32_16x16x32_bf16(a0h, bl, acc0, 0, 0, 0);
        acc1 = __builtin_amdgcn_mfma_f32_16x16x32_bf16(a1h, bl, acc1, 0, 0, 0);
    }
    int ncol = n0 + wid * 16 + r;
#pragma unroll
    for (int q = 0; q < 4; q++) {
        int m = kg * 4 + q;
        out[(size_t)(m0 + m) * Np + ncol]      = acc0[q];
        out[(size_t)(m0 + m + 16) * Np + ncol] = acc1[q];
    }
}

// ---------------- M=32 GEMM (split precision), k-split partials: part[kb][32][Np] ----------------
__global__ __launch_bounds__(256) void gemm32s_k(const unsigned short* __restrict__ Ahi,
                                                 const unsigned short* __restrict__ Alo,
                                                 const unsigned short* __restrict__ Whi,
                                                 const unsigned short* __restrict__ Wlo,
                                                 float* __restrict__ part,
                                                 int Kld, int Np, int ksteps) {
    int n0 = blockIdx.x * 64;
    int kb = blockIdx.y;
    int k0 = kb * ksteps * 32;
    int wid = threadIdx.x >> 6, lane = threadIdx.x & 63;
    int r = lane & 15, kg = lane >> 4;
    size_t woff = (size_t)(n0 + wid * 16 + r) * Kld + k0 + kg * 8;
    const unsigned short* Whr = Whi + woff;
    const unsigned short* Wlr = Wlo + woff;
    size_t aoff = (size_t)r * Kld + k0 + kg * 8;
    const unsigned short* Ah0 = Ahi + aoff;
    const unsigned short* Ah1 = Ah0 + (size_t)16 * Kld;
    const unsigned short* Al0 = Alo + aoff;
    const unsigned short* Al1 = Al0 + (size_t)16 * Kld;
    f4v acc0 = {0.f, 0.f, 0.f, 0.f}, acc1 = {0.f, 0.f, 0.f, 0.f};
#pragma unroll
    for (int s = 0; s < ksteps; s++) {
        s8v bh = *(const s8v*)(Whr + s * 32);
        s8v bl = *(const s8v*)(Wlr + s * 32);
        s8v a0h = *(const s8v*)(Ah0 + s * 32);
        s8v a1h = *(const s8v*)(Ah1 + s * 32);
        s8v a0l = *(const s8v*)(Al0 + s * 32);
        s8v a1l = *(const s8v*)(Al1 + s * 32);
        acc0 = __builtin_amdgcn_mfma_f32_16x16x32_bf16(a0h, bh, acc0, 0, 0, 0);
        acc1 = __builtin_amdgcn_mfma_f32_16x16x32_bf16(a1h, bh, acc1, 0, 0, 0);
        acc0 = __builtin_amdgcn_mfma_f32_16x16x32_bf16(a0l, bh, acc0, 0, 0, 0);
        acc1 = __builtin_amdgcn_mfma_f32_16x16x32_bf16(a1l, bh, acc1, 0, 0, 0);
        acc0 = __builtin_amdgcn_mfma_f32_16x16x32_bf16(a0h, bl, acc0, 0, 0, 0);
        acc1 = __builtin_amdgcn_mfma_f32_16x16x32_bf16(a1h, bl, acc1, 0, 0, 0);
    }
    int ncol = n0 + wid * 16 + r;
    float* p = part + (size_t)kb * 32 * Np + ncol;
#pragma unroll
    for (int q = 0; q < 4; q++) {
        int m = kg * 4 + q;
        p[(size_t)m * Np]        = acc0[q];
        p[(size_t)(m + 16) * Np] = acc1[q];
    }
}

// ---------------- M=32 GEMM plain bf16, k-split partials with slot base ----------------
__global__ __launch_bounds__(256) void gemm32_k(const unsigned short* __restrict__ A,
                                                const unsigned short* __restrict__ W,
                                                float* __restrict__ part,
                                                int Kld, int Np, int ksteps, int slot_base) {
    int n0 = blockIdx.x * 64;
    int kb = blockIdx.y;
    int k0 = kb * ksteps * 32;
    int wid = threadIdx.x >> 6, lane = threadIdx.x & 63;
    int r = lane & 15, kg = lane >> 4;
    const unsigned short* Wrow = W + (size_t)(n0 + wid * 16 + r) * Kld + k0 + kg * 8;
    const unsigned short* Ar0 = A + (size_t)r * Kld + k0 + kg * 8;
    const unsigned short* Ar1 = Ar0 + (size_t)16 * Kld;
    f4v acc0 = {0.f, 0.f, 0.f, 0.f}, acc1 = {0.f, 0.f, 0.f, 0.f};
#pragma unroll
    for (int s = 0; s < ksteps; s++) {
        s8v bf = *(const s8v*)(Wrow + s * 32);
        s8v a0 = *(const s8v*)(Ar0 + s * 32);
        s8v a1 = *(const s8v*)(Ar1 + s * 32);
        acc0 = __builtin_amdgcn_mfma_f32_16x16x32_bf16(a0, bf, acc0, 0, 0, 0);
        acc1 = __builtin_amdgcn_mfma_f32_16x16x32_bf16(a1, bf, acc1, 0, 0, 0);
    }
    int ncol = n0 + wid * 16 + r;
    float* p = part + (size_t)(slot_base + kb) * 32 * Np + ncol;
#pragma unroll
    for (int q = 0; q < 4; q++) {
        int m = kg * 4 + q;
        p[(size_t)m * Np]        = acc0[q];
        p[(size_t)(m + 16) * Np] = acc1[q];
    }
}

// ---------------- generic epilogue: reduce slots + bias (+tanh) -> bf16 ----------------
__global__ void epi_k(const float* __restrict__ part, int nslots, int Np, int realN,
                      const float* __restrict__ bias, int act,
                      unsigned short* __restrict__ outbf) {
    int gid = blockIdx.x * 256 + threadIdx.x;
    int b = gid / Np, n = gid % Np;
    float v = 0.0f;
    if (n < realN) {
        v = bias ? bias[n] : 0.0f;
        for (int s = 0; s < nslots; s++) v += part[(size_t)(s * 32 + b) * Np + n];
        if (act) v = tanhf(v);
    }
    outbf[(size_t)b * Np + n] = f2bf(v);
}

// ---------------- step S1: reduce + f32 x-part + tanh + LN -> h1 hi/lo + snapshot ----------------
__global__ void s1b_k(const float* __restrict__ part, const float* __restrict__ xw1,
                      const float* __restrict__ bias1c, const float* __restrict__ g,
                      const float* __restrict__ be, unsigned short* __restrict__ h1hi,
                      unsigned short* __restrict__ h1lo, unsigned short* __restrict__ h1snap) {
    int b = blockIdx.x, tid = threadIdx.x;
    __shared__ float sh[HP];
    __shared__ float r1[4], r2[4];
    float s = 0.f, s2 = 0.f;
    for (int i = 0; i < 13; i++) {
        int n = tid + i * 256;
        if (n >= HP) break;
        float v = 0.f;
        if (n < HH) {
            v = bias1c[n] + xw1[(size_t)b * HP + n];
            for (int kb = 0; kb < 7; kb++) v += part[(size_t)(kb * 32 + b) * HP + n];
            v = tanhf(v);
            s += v; s2 += v * v;
        }
        sh[n] = v;
    }
    for (int o = 32; o; o >>= 1) { s += __shfl_xor(s, o); s2 += __shfl_xor(s2, o); }
    int wid = tid >> 6, lane = tid & 63;
    if (lane == 0) { r1[wid] = s; r2[wid] = s2; }
    __syncthreads();
    s = r1[0] + r1[1] + r1[2] + r1[3];
    s2 = r2[0] + r2[1] + r2[2] + r2[3];
    float m = s / (float)HH;
    float var = s2 / (float)HH - m * m;
    float inv = rsqrtf(var + 1e-5f);
    for (int i = 0; i < 13; i++) {
        int n = tid + i * 256;
        if (n >= HP) break;
        float o = 0.f;
        if (n < HH) o = (sh[n] - m) * inv * g[n] + be[n];
        unsigned short hb = f2bf(o);
        size_t idx = (size_t)b * HP + n;
        h1hi[idx] = hb;
        h1lo[idx] = f2bf(o - bf2f(hb));
        h1snap[idx] = hb;
    }
}

// ---------------- step S2: reduce + whh2 GEMV (f32 state) + tanh ----------------
__global__ void s2b_k(const float* __restrict__ part2, const float* __restrict__ h2old,
                      const unsigned short* __restrict__ whh2t, const float* __restrict__ bias2c,
                      float* __restrict__ h2new, unsigned short* __restrict__ h2s) {
    int gid = blockIdx.x * 256 + threadIdx.x;
    int b = gid / EE, n = gid % EE;
    float v = bias2c[n];
    for (int kb = 0; kb < 7; kb++) v += part2[(size_t)(kb * 32 + b) * EE + n];
    const float* h = h2old + (size_t)b * EE;
#pragma unroll 8
    for (int k = 0; k < EE; k++) v += h[k] * bf2f(whh2t[(size_t)k * EE + n]);
    v = tanhf(v);
    h2new[(size_t)b * EE + n] = v;
    h2s[(size_t)b * EE + n] = f2bf(v);
}

// ---------------- qbk[b] = sum_d q[b][d]*bk[d] ----------------
__global__ void qbk_k(const unsigned short* __restrict__ q, int Kp, int realK,
                      const float* __restrict__ bk, float* __restrict__ out) {
    int b = blockIdx.x, tid = threadIdx.x;
    float s = 0.f;
    for (int d = tid; d < realK; d += 256) s += bf2f(q[(size_t)b * Kp + d]) * bk[d];
    for (int o = 32; o; o >>= 1) s += __shfl_xor(s, o);
    __shared__ float r[4];
    if ((tid & 63) == 0) r[tid >> 6] = s;
    __syncthreads();
    if (tid == 0) out[b] = r[0] + r[1] + r[2] + r[3];
}

// ---------------- scores[b][t] = (qk[b]·hs[t][b] + qbk[b]) * scale ----------------
__global__ void scores_k(const unsigned short* __restrict__ hs, const unsigned short* __restrict__ qk,
                         const float* __restrict__ qbk, float* __restrict__ out,
                         int Kp, float scale) {
    int gid = blockIdx.x * 4 + (threadIdx.x >> 6);
    int lane = threadIdx.x & 63;
    int b = gid >> 9, t = gid & 511;
    const unsigned short* hrow = hs + (size_t)(t * BB + b) * Kp;
    const unsigned short* qrow = qk + (size_t)b * Kp;
    float acc = 0.f;
    for (int kb = lane * 4; kb < Kp; kb += 256) {
        uint2 hv = *reinterpret_cast<const uint2*>(hrow + kb);
        uint2 qv = *reinterpret_cast<const uint2*>(qrow + kb);
        acc += __uint_as_float(hv.x << 16) * __uint_as_float(qv.x << 16);
        acc += __uint_as_float(hv.x & 0xFFFF0000u) * __uint_as_float(qv.x & 0xFFFF0000u);
        acc += __uint_as_float(hv.y << 16) * __uint_as_float(qv.y << 16);
        acc += __uint_as_float(hv.y & 0xFFFF0000u) * __uint_as_float(qv.y & 0xFFFF0000u);
    }
    for (int o = 32; o; o >>= 1) acc += __shfl_xor(acc, o);
    if (lane == 0) out[b * TT + t] = (acc + qbk[b]) * scale;
}

// ---------------- softmax over 512 per b ----------------
__global__ void softmax_k(const float* __restrict__ in, float* __restrict__ out) {
    int b = blockIdx.x, tid = threadIdx.x;
    float v0 = in[b * TT + tid], v1 = in[b * TT + 256 + tid];
    float mx = fmaxf(v0, v1);
    for (int o = 32; o; o >>= 1) mx = fmaxf(mx, __shfl_xor(mx, o));
    __shared__ float r[4], r2[4];
    int wid = tid >> 6, lane = tid & 63;
    if (lane == 0) r[wid] = mx;
    __syncthreads();
    mx = fmaxf(fmaxf(r[0], r[1]), fmaxf(r[2], r[3]));
    float e0 = expf(v0 - mx), e1 = expf(v1 - mx);
    float s = e0 + e1;
    for (int o = 32; o; o >>= 1) s += __shfl_xor(s, o);
    if (lane == 0) r2[wid] = s;
    __syncthreads();
    s = r2[0] + r2[1] + r2[2] + r2[3];
    float invs = 1.0f / s;
    out[b * TT + tid] = e0 * invs;
    out[b * TT + 256 + tid] = e1 * invs;
}

// ---------------- u[b][e] = sum_t a[b][t]*hs[t][b][e] ----------------
__global__ void attnsum_k(const unsigned short* __restrict__ hs, const float* __restrict__ aw,
                          unsigned short* __restrict__ out, int Kp) {
    int gid = blockIdx.x * 256 + threadIdx.x;
    int b = gid / Kp, e = gid % Kp;
    float acc = 0.f;
    for (int t = 0; t < TT; t++)
        acc += aw[b * TT + t] * bf2f(hs[((size_t)t * BB + b) * Kp + e]);
    out[(size_t)b * Kp + e] = f2bf(acc);
}

// ---------------- classifier ----------------
__global__ void cls_k(const unsigned short* __restrict__ h2f, const float* __restrict__ wcls,
                      const float* __restrict__ bcls, float* __restrict__ out) {
    int b = blockIdx.x;
    int wid = threadIdx.x >> 6, lane = threadIdx.x & 63;
    for (int o = wid; o < OO; o += 4) {
        float s = 0.f;
        for (int e = lane; e < EE; e += 64)
            s += bf2f(h2f[(size_t)b * EE + e]) * wcls[o * EE + e];
        for (int off = 32; off; off >>= 1) s += __shfl_xor(s, off);
        if (lane == 0) out[b * OO + o] = s + bcls[o];
    }
}

__global__ void fail_k(float* out) {
    int i = blockIdx.x * 256 + threadIdx.x;
    if (i < BB * OO) out[i] = 1e9f;
}

// =====================================================================
extern "C" void kernel_launch(void* const* d_in, const int* in_sizes, int n_in,
                              void* d_out, int out_size, void* d_ws, size_t ws_size,
                              hipStream_t stream) {
    const float* x        = (const float*)d_in[0];
    const float* in_g     = (const float*)d_in[1];
    const float* in_b     = (const float*)d_in[2];
    const float* w_ih1    = (const float*)d_in[3];
    const float* w_hh1    = (const float*)d_in[4];
    const float* b_ih1    = (const float*)d_in[5];
    const float* b_hh1    = (const float*)d_in[6];
    const float* ln1_g    = (const float*)d_in[7];
    const float* ln1_b    = (const float*)d_in[8];
    const float* w_ih2    = (const float*)d_in[9];
    const float* w_hh2    = (const float*)d_in[10];
    const float* b_ih2    = (const float*)d_in[11];
    const float* b_hh2    = (const float*)d_in[12];
    const float* m1_wqkv  = (const float*)d_in[13];
    const float* m1_bqkv  = (const float*)d_in[14];
    const float* m1_wo    = (const float*)d_in[15];
    const float* m1_bo    = (const float*)d_in[16];
    const float* m2_wqkv  = (const float*)d_in[17];
    const float* m2_bqkv  = (const float*)d_in[18];
    const float* m2_wo    = (const float*)d_in[19];
    const float* m2_bo    = (const float*)d_in[20];
    const float* w_cls    = (const float*)d_in[21];
    const float* b_cls    = (const float*)d_in[22];
    float* out = (float*)d_out;

    const size_t TB = (size_t)TT * BB;
    // ---- workspace layout (~343 MB; round-1 proved ws >= ~377 MB) ----
    size_t cur = 0;
    auto alloc = [&](size_t bytes) { cur = (cur + 255) & ~(size_t)255; size_t o = cur; cur += bytes; return o; };
    char* ws = (char*)d_ws;
    #define US(off) ((unsigned short*)(ws + (off)))
    #define FP(off) ((float*)(ws + (off)))

    size_t o_xnhi   = alloc(TB * EE * 2);
    size_t o_xnlo   = alloc(TB * EE * 2);
    size_t o_wih1hi = alloc((size_t)HP * EE * 2);
    size_t o_wih1lo = alloc((size_t)HP * EE * 2);
    size_t o_whh1hi = alloc((size_t)HP * HP * 2);
    size_t o_whh1lo = alloc((size_t)HP * HP * 2);
    size_t o_wih2   = alloc((size_t)EE * HP * 2);
    size_t o_whh2t  = alloc((size_t)EE * EE * 2);
    size_t o_xw1    = alloc((size_t)(TT / 2) * BB * HP * 4);  // f32, half-T chunk (refilled mid-loop)
    size_t o_h1s    = alloc(TB * HP * 2);
    size_t o_h2s    = alloc(TB * EE * 2);
    size_t o_h1hi   = alloc((size_t)BB * HP * 2);
    size_t o_h1lo   = alloc((size_t)BB * HP * 2);
    size_t o_h2buf  = alloc(2 * (size_t)BB * EE * 4);
    size_t o_part1  = alloc(8 * (size_t)BB * HP * 4);
    size_t o_part2  = alloc(8 * (size_t)BB * EE * 4);
    size_t o_b1c    = alloc((size_t)HP * 4);
    size_t o_b2c    = alloc((size_t)EE * 4);
    size_t o_q1     = alloc((size_t)BB * HP * 2);
    size_t o_qk1    = alloc((size_t)BB * HP * 2);
    size_t o_u1     = alloc((size_t)BB * HP * 2);
    size_t o_vc1    = alloc((size_t)BB * HP * 2);
    size_t o_ctx1   = alloc((size_t)BB * HP * 2);
    size_t o_qbk1   = alloc(BB * 4);
    size_t o_sc1    = alloc((size_t)BB * TT * 4);
    size_t o_aw1    = alloc((size_t)BB * TT * 4);
    size_t o_q2     = alloc((size_t)BB * EE * 2);
    size_t o_qk2    = alloc((size_t)BB * EE * 2);
    size_t o_u2     = alloc((size_t)BB * EE * 2);
    size_t o_vc2    = alloc((size_t)BB * EE * 2);
    size_t o_ctx2   = alloc((size_t)BB * EE * 2);
    size_t o_qbk2   = alloc(BB * 4);
    size_t o_sc2    = alloc((size_t)BB * TT * 4);
    size_t o_aw2    = alloc((size_t)BB * TT * 4);
    size_t o_h1f    = alloc((size_t)BB * HP * 2);
    size_t o_h2f    = alloc((size_t)BB * EE * 2);

    // overlay region for post-recurrence weights, inside the xw1 chunk (dead after loop)
    size_t ov = o_xw1;
    auto oalloc = [&](size_t bytes) { ov = (ov + 255) & ~(size_t)255; size_t o = ov; ov += bytes; return o; };
    size_t v_wq1  = oalloc((size_t)HP * HP * 2);
    size_t v_wk1T = oalloc((size_t)HP * HP * 2);
    size_t v_wv1  = oalloc((size_t)HP * HP * 2);
    size_t v_wo1  = oalloc((size_t)HP * HP * 2);
    size_t v_whh2 = oalloc((size_t)EE * EE * 2);
    size_t v_wq2  = oalloc((size_t)EE * EE * 2);
    size_t v_wk2T = oalloc((size_t)EE * EE * 2);
    size_t v_wv2  = oalloc((size_t)EE * EE * 2);
    size_t v_wo2  = oalloc((size_t)EE * EE * 2);
    // (84.6 MB used of the 102.8 MB xw1 chunk)

    if (ws_size < cur) {   // workspace too small -> unambiguous sentinel
        fail_k<<<3, 256, 0, stream>>>(out);
        return;
    }

    // ---------- prep ----------
    ln_x_k<<<BB * TT, 256, 0, stream>>>(x, in_g, in_b, US(o_xnhi), US(o_xnlo));
    castsplit_k<<<(HP * EE + 255) / 256, 256, 0, stream>>>(w_ih1, HH, EE, US(o_wih1hi), US(o_wih1lo), HP, EE);
    castsplit_k<<<(HP * HP + 255) / 256, 256, 0, stream>>>(w_hh1, HH, HH, US(o_whh1hi), US(o_whh1lo), HP, HP);
    castpad_k<<<(EE * HP + 255) / 256, 256, 0, stream>>>(w_ih2, EE, HH, US(o_wih2), EE, HP);
    transcast_k<<<dim3(EE / 32, EE / 32), 256, 0, stream>>>(w_hh2, EE, EE, US(o_whh2t), EE, EE);
    biascomb_k<<<(HP + 255) / 256, 256, 0, stream>>>(b_ih1, b_hh1, FP(o_b1c), HH, HP);
    biascomb_k<<<(EE + 255) / 256, 256, 0, stream>>>(b_ih2, b_hh2, FP(o_b2c), EE, EE);
    hipMemsetAsync(US(o_h1hi), 0, (size_t)BB * HP * 2, stream);
    hipMemsetAsync(US(o_h1lo), 0, (size_t)BB * HP * 2, stream);
    hipMemsetAsync(FP(o_h2buf), 0, 2 * (size_t)BB * EE * 4, stream);

    // xw1 chunk A: rows 0..8191 (t in [0,256)), split-precision, f32 out
    gemmbig_k<<<dim3(256, HP / 64), 256, 0, stream>>>(US(o_xnhi), US(o_xnlo),
                                                      US(o_wih1hi), US(o_wih1lo),
                                                      FP(o_xw1), EE, HP, EE / 32);

    // ---------- sequential RNN ----------
    for (int t = 0; t < TT; t++) {
        if (t == 256) {  // refill xw1 with chunk B: rows 8192..16383 (stream-ordered, race-free)
            gemmbig_k<<<dim3(256, HP / 64), 256, 0, stream>>>(US(o_xnhi) + (size_t)8192 * EE,
                                                              US(o_xnlo) + (size_t)8192 * EE,
                                                              US(o_wih1hi), US(o_wih1lo),
                                                              FP(o_xw1), EE, HP, EE / 32);
        }
        gemm32s_k<<<dim3(HP / 64, 7), 256, 0, stream>>>(US(o_h1hi), US(o_h1lo),
                                                        US(o_whh1hi), US(o_whh1lo),
                                                        FP(o_part1), HP, HP, 14);
        s1b_k<<<BB, 256, 0, stream>>>(FP(o_part1), FP(o_xw1) + (size_t)(t & 255) * BB * HP,
                                      FP(o_b1c), ln1_g, ln1_b,
                                      US(o_h1hi), US(o_h1lo), US(o_h1s) + (size_t)t * BB * HP);
        gemm32_k<<<dim3(EE / 64, 7), 256, 0, stream>>>(US(o_h1hi), US(o_wih2), FP(o_part2), HP, EE, 14, 0);
        s2b_k<<<BB * EE / 256, 256, 0, stream>>>(FP(o_part2), FP(o_h2buf) + (size_t)(t & 1) * BB * EE,
                                                 US(o_whh2t), FP(o_b2c),
                                                 FP(o_h2buf) + (size_t)((t + 1) & 1) * BB * EE,
                                                 US(o_h2s) + (size_t)t * BB * EE);
    }

    // ---------- cast post-recurrence weights into overlay (xw1 now dead) ----------
    auto cast = [&](const float* in, int N, int K, size_t off, int Np, int Kp) {
        size_t tot = (size_t)Np * Kp;
        castpad_k<<<(int)((tot + 255) / 256), 256, 0, stream>>>(in, N, K, US(off), Np, Kp);
    };
    cast(m1_wqkv,                        HH, HH, v_wq1, HP, HP);
    cast(m1_wqkv + (size_t)2 * HH * HH,  HH, HH, v_wv1, HP, HP);
    cast(m1_wo,                          HH, HH, v_wo1, HP, HP);
    transcast_k<<<dim3(HP / 32, HP / 32), 256, 0, stream>>>(m1_wqkv + (size_t)HH * HH, HH, HH, US(v_wk1T), HP, HP);
    cast(w_hh2, EE, EE, v_whh2, EE, EE);
    cast(m2_wqkv,                        EE, EE, v_wq2, EE, EE);
    cast(m2_wqkv + (size_t)2 * EE * EE,  EE, EE, v_wv2, EE, EE);
    cast(m2_wo,                          EE, EE, v_wo2, EE, EE);
    transcast_k<<<dim3(EE / 32, EE / 32), 256, 0, stream>>>(m2_wqkv + (size_t)EE * EE, EE, EE, US(v_wk2T), EE, EE);

    const float sc_scale1 = 1.0f / sqrtf((float)HH);
    const float sc_scale2 = 1.0f / sqrtf((float)EE);

    // ---------- MHA1 (only last-row context needed) ----------
    gemm32_k<<<dim3(HP / 64, 7), 256, 0, stream>>>(US(o_h1hi), US(v_wq1), FP(o_part1), HP, HP, 14, 0);
    epi_k<<<BB * HP / 256, 256, 0, stream>>>(FP(o_part1), 7, HP, HH, m1_bqkv, 0, US(o_q1));
    gemm32_k<<<dim3(HP / 64, 7), 256, 0, stream>>>(US(o_q1), US(v_wk1T), FP(o_part1), HP, HP, 14, 0);
    epi_k<<<BB * HP / 256, 256, 0, stream>>>(FP(o_part1), 7, HP, HH, nullptr, 0, US(o_qk1));
    qbk_k<<<BB, 256, 0, stream>>>(US(o_q1), HP, HH, m1_bqkv + HH, FP(o_qbk1));
    scores_k<<<BB * TT / 4, 256, 0, stream>>>(US(o_h1s), US(o_qk1), FP(o_qbk1), FP(o_sc1), HP, sc_scale1);
    softmax_k<<<BB, 256, 0, stream>>>(FP(o_sc1), FP(o_aw1));
    attnsum_k<<<BB * HP / 256, 256, 0, stream>>>(US(o_h1s), FP(o_aw1), US(o_u1), HP);
    gemm32_k<<<dim3(HP / 64, 7), 256, 0, stream>>>(US(o_u1), US(v_wv1), FP(o_part1), HP, HP, 14, 0);
    epi_k<<<BB * HP / 256, 256, 0, stream>>>(FP(o_part1), 7, HP, HH, m1_bqkv + 2 * HH, 0, US(o_vc1));
    gemm32_k<<<dim3(HP / 64, 7), 256, 0, stream>>>(US(o_vc1), US(v_wo1), FP(o_part1), HP, HP, 14, 0);
    epi_k<<<BB * HP / 256, 256, 0, stream>>>(FP(o_part1), 7, HP, HH, m1_bo, 0, US(o_ctx1));

    // ---------- MHA2 ----------
    const unsigned short* h2last = US(o_h2s) + (size_t)(TT - 1) * BB * EE;
    gemm32_k<<<dim3(EE / 64, 3), 256, 0, stream>>>(h2last, US(v_wq2), FP(o_part2), EE, EE, 8, 0);
    epi_k<<<BB * EE / 256, 256, 0, stream>>>(FP(o_part2), 3, EE, EE, m2_bqkv, 0, US(o_q2));
    gemm32_k<<<dim3(EE / 64, 3), 256, 0, stream>>>(US(o_q2), US(v_wk2T), FP(o_part2), EE, EE, 8, 0);
    epi_k<<<BB * EE / 256, 256, 0, stream>>>(FP(o_part2), 3, EE, EE, nullptr, 0, US(o_qk2));
    qbk_k<<<BB, 256, 0, stream>>>(US(o_q2), EE, EE, m2_bqkv + EE, FP(o_qbk2));
    scores_k<<<BB * TT / 4, 256, 0, stream>>>(US(o_h2s), US(o_qk2), FP(o_qbk2), FP(o_sc2), EE, sc_scale2);
    softmax_k<<<BB, 256, 0, stream>>>(FP(o_sc2), FP(o_aw2));
    attnsum_k<<<BB * EE / 256, 256, 0, stream>>>(US(o_h2s), FP(o_aw2), US(o_u2), EE);
    gemm32_k<<<dim3(EE / 64, 3), 256, 0, stream>>>(US(o_u2), US(v_wv2), FP(o_part2), EE, EE, 8, 0);
    epi_k<<<BB * EE / 256, 256, 0, stream>>>(FP(o_part2), 3, EE, EE, m2_bqkv + 2 * EE, 0, US(o_vc2));
    gemm32_k<<<dim3(EE / 64, 3), 256, 0, stream>>>(US(o_vc2), US(v_wo2), FP(o_part2), EE, EE, 8, 0);
    epi_k<<<BB * EE / 256, 256, 0, stream>>>(FP(o_part2), 3, EE, EE, m2_bo, 0, US(o_ctx2));

    // ---------- final cells ----------
    const unsigned short* xnlast = US(o_xnhi) + (size_t)(TT - 1) * BB * EE;
    gemm32_k<<<dim3(HP / 64, 1), 256, 0, stream>>>(xnlast, US(o_wih1hi), FP(o_part1), EE, HP, EE / 32, 0);
    gemm32_k<<<dim3(HP / 64, 7), 256, 0, stream>>>(US(o_ctx1), US(o_whh1hi), FP(o_part1), HP, HP, 14, 1);
    epi_k<<<BB * HP / 256, 256, 0, stream>>>(FP(o_part1), 8, HP, HH, FP(o_b1c), 1, US(o_h1f));
    gemm32_k<<<dim3(EE / 64, 7), 256, 0, stream>>>(US(o_h1f), US(o_wih2), FP(o_part2), HP, EE, 14, 0);
    gemm32_k<<<dim3(EE / 64, 1), 256, 0, stream>>>(US(o_ctx2), US(v_whh2), FP(o_part2), EE, EE, EE / 32, 7);
    epi_k<<<BB * EE / 256, 256, 0, stream>>>(FP(o_part2), 8, EE, EE, FP(o_b2c), 1, US(o_h2f));
    cls_k<<<BB, 256, 0, stream>>>(US(o_h2f), w_cls, b_cls, out);
}